// Round 1
// baseline (556.759 us; speedup 1.0000x reference)
//
#include <hip/hip_runtime.h>
#include <hip/hip_bf16.h>

typedef unsigned short u16;
typedef __bf16 bf16x8 __attribute__((ext_vector_type(8)));
typedef short  short8 __attribute__((ext_vector_type(8)));
typedef float  f32x4  __attribute__((ext_vector_type(4)));

#define BB 2
#define SS 2048
#define DD 2048
#define HH 16
#define HDIM 128

static __device__ __forceinline__ f32x4 mfma16(short8 a, short8 b, f32x4 c) {
    return __builtin_amdgcn_mfma_f32_16x16x32_bf16(
        __builtin_bit_cast(bf16x8, a), __builtin_bit_cast(bf16x8, b), c, 0, 0, 0);
}

static __device__ __forceinline__ u16 f2bf(float f) {
    union { float f; unsigned u; } v; v.f = f;
    unsigned r = v.u + 0x7fffu + ((v.u >> 16) & 1u);
    return (u16)(r >> 16);
}

static __device__ __forceinline__ uint4 pack8(float4 a, float4 b) {
    uint4 o;
    o.x = (unsigned)f2bf(a.x) | ((unsigned)f2bf(a.y) << 16);
    o.y = (unsigned)f2bf(a.z) | ((unsigned)f2bf(a.w) << 16);
    o.z = (unsigned)f2bf(b.x) | ((unsigned)f2bf(b.y) << 16);
    o.w = (unsigned)f2bf(b.z) | ((unsigned)f2bf(b.w) << 16);
    return o;
}

// C[M][N] = A[M][K] @ W[N][K]^T + bias   (torch x @ W.T + b convention)
// A: fp32 or bf16 per A_BF16. C: bf16 or fp32 per C_BF16. W, bias always fp32.
template<bool A_BF16, bool C_BF16>
__global__ __launch_bounds__(256) void gemm_wt_bias(
    const void* __restrict__ Ap, const float* __restrict__ W,
    const float* __restrict__ bias, void* __restrict__ Cp,
    int M, int N, int K)
{
    constexpr int SA = 40;              // padded LDS row stride (elems): 80B, banks spread
    __shared__ u16 Al[128 * SA];
    __shared__ u16 Bl[128 * SA];

    const int tid = threadIdx.x;
    const int wid = tid >> 6, lane = tid & 63;
    const int lg = lane >> 4, li = lane & 15;
    const int brow = blockIdx.x * 128, bcol = blockIdx.y * 128;
    const int wm = wid >> 1, wn = wid & 1;
    const int sr = tid >> 1;            // staging row 0..127
    const int sc = (tid & 1) * 16;      // staging col 0 or 16

    const f32x4 zero = {0.f, 0.f, 0.f, 0.f};
    f32x4 acc[4][4];
#pragma unroll
    for (int i = 0; i < 4; ++i)
#pragma unroll
        for (int j = 0; j < 4; ++j) acc[i][j] = zero;

    const float* __restrict__ Af = (const float*)Ap;
    const u16*   __restrict__ Ab = (const u16*)Ap;

    for (int kt = 0; kt < K; kt += 32) {
        // ---- stage A tile (128 rows x 32 k) ----
        if (A_BF16) {
            const uint4* src = (const uint4*)(Ab + (size_t)(brow + sr) * K + kt + sc);
            uint4 a0 = src[0], a1 = src[1];
            *(uint4*)(&Al[sr * SA + sc])     = a0;
            *(uint4*)(&Al[sr * SA + sc + 8]) = a1;
        } else {
            const float4* src = (const float4*)(Af + (size_t)(brow + sr) * K + kt + sc);
            float4 f0 = src[0], f1 = src[1], f2 = src[2], f3 = src[3];
            *(uint4*)(&Al[sr * SA + sc])     = pack8(f0, f1);
            *(uint4*)(&Al[sr * SA + sc + 8]) = pack8(f2, f3);
        }
        // ---- stage B tile: W rows [bcol .. bcol+127], fp32 -> bf16 ----
        {
            const float4* src = (const float4*)(W + (size_t)(bcol + sr) * K + kt + sc);
            float4 f0 = src[0], f1 = src[1], f2 = src[2], f3 = src[3];
            *(uint4*)(&Bl[sr * SA + sc])     = pack8(f0, f1);
            *(uint4*)(&Bl[sr * SA + sc + 8]) = pack8(f2, f3);
        }
        __syncthreads();

        short8 af[4], bfr[4];
#pragma unroll
        for (int mi = 0; mi < 4; ++mi)
            af[mi] = *(const short8*)(&Al[(wm * 64 + mi * 16 + li) * SA + lg * 8]);
#pragma unroll
        for (int ni = 0; ni < 4; ++ni)
            bfr[ni] = *(const short8*)(&Bl[(wn * 64 + ni * 16 + li) * SA + lg * 8]);
#pragma unroll
        for (int mi = 0; mi < 4; ++mi)
#pragma unroll
            for (int ni = 0; ni < 4; ++ni)
                acc[mi][ni] = mfma16(af[mi], bfr[ni], acc[mi][ni]);
        __syncthreads();
    }

    // epilogue: C layout col=lane&15, row=(lane>>4)*4+reg (m89-verified)
#pragma unroll
    for (int ni = 0; ni < 4; ++ni) {
        const int col = bcol + wn * 64 + ni * 16 + li;
        const float bv = bias[col];
#pragma unroll
        for (int mi = 0; mi < 4; ++mi) {
#pragma unroll
            for (int r = 0; r < 4; ++r) {
                const int row = brow + wm * 64 + mi * 16 + lg * 4 + r;
                const float v = acc[mi][ni][r] + bv;
                if (C_BF16) ((u16*)Cp)[(size_t)row * N + col] = f2bf(v);
                else        ((float*)Cp)[(size_t)row * N + col] = v;
            }
        }
    }
}

// Flash attention, causal. Q,K,V,O: bf16 [B*S][D], head h at cols h*128..h*128+127.
// Block: one (b, h, 64-row q-tile). 4 waves x 16 q-rows each. KV tile = 64.
__global__ __launch_bounds__(256) void flash_attn(
    const u16* __restrict__ Q, const u16* __restrict__ Kp,
    const u16* __restrict__ Vp, u16* __restrict__ O)
{
    constexpr int SK = 136;   // K_lds row stride (elems), 272B: b128 reads 2-way (free)
    constexpr int SV = 72;    // Vt row stride (elems), 144B
    constexpr int SP = 72;
    __shared__ u16 Kl[64 * SK];        // K tile [kv][d]
    __shared__ u16 Vt[HDIM * SV];      // V tile transposed [d][kv], kv chunk-XOR-swizzled
    __shared__ u16 Pl[4 * 16 * SP];    // per-wave P [16][64]

    const int tid = threadIdx.x;
    const int wid = tid >> 6, lane = tid & 63;
    const int lg = lane >> 4, li = lane & 15;
    const int qt = (int)gridDim.x - 1 - (int)blockIdx.x;  // heavy tiles launch first
    const int h = blockIdx.y, b = blockIdx.z;

    // fold 1/sqrt(128) and log2(e): softmax done in exp2 domain
    const float kscale = 0.08838834764831845f * 1.44269504088896f;

    short8 qf[4];
    {
        const u16* qp = Q + (size_t)(b * SS + qt * 64 + wid * 16 + li) * DD + h * HDIM + lg * 8;
#pragma unroll
        for (int s = 0; s < 4; ++s) qf[s] = *(const short8*)(qp + s * 32);
    }

    const f32x4 zero = {0.f, 0.f, 0.f, 0.f};
    float m_r[4], l_r[4];
    f32x4 accO[8];
#pragma unroll
    for (int r = 0; r < 4; ++r) { m_r[r] = -__builtin_inff(); l_r[r] = 0.f; }
#pragma unroll
    for (int d = 0; d < 8; ++d) accO[d] = zero;

    const int sr  = tid >> 2;          // kv row 0..63
    const int sc4 = (tid & 3) * 32;    // d chunk base

    for (int kt = 0; kt <= qt; ++kt) {
        // ---- stage K tile and V^T tile ----
        {
            const size_t base = (size_t)(b * SS + kt * 64 + sr) * DD + h * HDIM + sc4;
            const uint4* ks = (const uint4*)(Kp + base);
            uint4* kd = (uint4*)(&Kl[sr * SK + sc4]);
#pragma unroll
            for (int c = 0; c < 4; ++c) kd[c] = ks[c];
            const uint4* vs = (const uint4*)(Vp + base);
#pragma unroll
            for (int c = 0; c < 4; ++c) {
                uint4 u = vs[c];
                const int d0 = sc4 + c * 8;                 // d0 % 8 == 0
                const int x  = ((sr >> 3) ^ ((d0 >> 3) & 7)) << 3;
                const int boff = d0 * SV + x + (sr & 7);
                Vt[boff + 0 * SV] = (u16)(u.x);
                Vt[boff + 1 * SV] = (u16)(u.x >> 16);
                Vt[boff + 2 * SV] = (u16)(u.y);
                Vt[boff + 3 * SV] = (u16)(u.y >> 16);
                Vt[boff + 4 * SV] = (u16)(u.z);
                Vt[boff + 5 * SV] = (u16)(u.z >> 16);
                Vt[boff + 6 * SV] = (u16)(u.w);
                Vt[boff + 7 * SV] = (u16)(u.w >> 16);
            }
        }
        __syncthreads();

        // ---- scores: S[16 q][64 kv] per wave ----
        f32x4 accS[4] = {zero, zero, zero, zero};
#pragma unroll
        for (int s = 0; s < 4; ++s) {
#pragma unroll
            for (int nb = 0; nb < 4; ++nb) {
                short8 kf = *(const short8*)(&Kl[(nb * 16 + li) * SK + s * 32 + lg * 8]);
                accS[nb] = mfma16(qf[s], kf, accS[nb]);
            }
        }

        // ---- online softmax (exp2 domain) ----
        float p[4][4];
        float rmax[4];
#pragma unroll
        for (int r = 0; r < 4; ++r) rmax[r] = -__builtin_inff();
        const bool diag = (kt == qt);
#pragma unroll
        for (int nb = 0; nb < 4; ++nb)
#pragma unroll
            for (int r = 0; r < 4; ++r) {
                float t = accS[nb][r] * kscale;
                if (diag && (nb * 16 + li > wid * 16 + lg * 4 + r)) t = -__builtin_inff();
                p[nb][r] = t;
                rmax[r] = fmaxf(rmax[r], t);
            }
#pragma unroll
        for (int off = 1; off < 16; off <<= 1)
#pragma unroll
            for (int r = 0; r < 4; ++r)
                rmax[r] = fmaxf(rmax[r], __shfl_xor(rmax[r], off, 64));

        float sf[4], ls[4];
#pragma unroll
        for (int r = 0; r < 4; ++r) {
            const float mn = fmaxf(m_r[r], rmax[r]);   // finite: diag row always has col<=row
            sf[r] = exp2f(m_r[r] - mn);                // first iter: exp2(-inf)=0
            m_r[r] = mn;
            ls[r] = 0.f;
        }
#pragma unroll
        for (int nb = 0; nb < 4; ++nb)
#pragma unroll
            for (int r = 0; r < 4; ++r) {
                const float e = exp2f(p[nb][r] - m_r[r]);  // masked -> 0
                p[nb][r] = e;
                ls[r] += e;
            }
#pragma unroll
        for (int off = 1; off < 16; off <<= 1)
#pragma unroll
            for (int r = 0; r < 4; ++r)
                ls[r] += __shfl_xor(ls[r], off, 64);
#pragma unroll
        for (int r = 0; r < 4; ++r) l_r[r] = l_r[r] * sf[r] + ls[r];
#pragma unroll
        for (int d = 0; d < 8; ++d)
#pragma unroll
            for (int r = 0; r < 4; ++r) accO[d][r] *= sf[r];

        // ---- P -> LDS (per-wave region) ----
#pragma unroll
        for (int nb = 0; nb < 4; ++nb)
#pragma unroll
            for (int r = 0; r < 4; ++r)
                Pl[(wid * 16 + lg * 4 + r) * SP + nb * 16 + li] = f2bf(p[nb][r]);
        __syncthreads();

        // ---- PV: O[16 q][128 d] += P[16][64] @ V[64][128] ----
#pragma unroll
        for (int s2 = 0; s2 < 2; ++s2) {
            short8 pf = *(const short8*)(&Pl[(wid * 16 + li) * SP + s2 * 32 + lg * 8]);
#pragma unroll
            for (int db = 0; db < 8; ++db) {
                const int d  = db * 16 + li;
                const int cb = ((s2 * 4 + lg) ^ ((d >> 3) & 7)) << 3;
                short8 vf = *(const short8*)(&Vt[d * SV + cb]);
                accO[db] = mfma16(pf, vf, accO[db]);
            }
        }
        __syncthreads();
    }

    // ---- epilogue ----
#pragma unroll
    for (int db = 0; db < 8; ++db)
#pragma unroll
        for (int r = 0; r < 4; ++r) {
            const int row = qt * 64 + wid * 16 + lg * 4 + r;
            const float v = accO[db][r] / l_r[r];
            O[(size_t)(b * SS + row) * DD + h * HDIM + db * 16 + li] = f2bf(v);
        }
}

extern "C" void kernel_launch(void* const* d_in, const int* in_sizes, int n_in,
                              void* d_out, int out_size, void* d_ws, size_t ws_size,
                              hipStream_t stream)
{
    const float* queries = (const float*)d_in[0];
    const float* keys    = (const float*)d_in[1];
    const float* values  = (const float*)d_in[2];
    // d_in[3] = attention_mask: causal by construction, handled analytically
    const float* wq = (const float*)d_in[4];
    const float* bq = (const float*)d_in[5];
    const float* wk = (const float*)d_in[6];
    const float* bk = (const float*)d_in[7];
    const float* wv = (const float*)d_in[8];
    const float* bv = (const float*)d_in[9];
    const float* wo = (const float*)d_in[10];
    const float* bo = (const float*)d_in[11];

    const int M = BB * SS;                      // 4096
    u16* qw = (u16*)d_ws;                       // bf16 q   [M][D]
    u16* kw = qw + (size_t)M * DD;              // bf16 k
    u16* vw = kw + (size_t)M * DD;              // bf16 v
    u16* aw = vw + (size_t)M * DD;              // bf16 attn out
    (void)in_sizes; (void)n_in; (void)out_size; (void)ws_size;

    dim3 gridG(M / 128, DD / 128);              // (32, 16)
    dim3 gridA(SS / 64, HH, BB);                // (32, 16, 2)
    dim3 blk(256);

    gemm_wt_bias<false, true><<<gridG, blk, 0, stream>>>(queries, wq, bq, qw, M, DD, DD);
    gemm_wt_bias<false, true><<<gridG, blk, 0, stream>>>(keys,    wk, bk, kw, M, DD, DD);
    gemm_wt_bias<false, true><<<gridG, blk, 0, stream>>>(values,  wv, bv, vw, M, DD, DD);
    flash_attn<<<gridA, blk, 0, stream>>>(qw, kw, vw, aw);
    gemm_wt_bias<true, false><<<gridG, blk, 0, stream>>>(aw, wo, bo, (float*)d_out, M, DD, DD);
}

// Round 2
// 483.907 us; speedup vs baseline: 1.1506x; 1.1506x over previous
//
#include <hip/hip_runtime.h>
#include <hip/hip_bf16.h>

typedef unsigned short u16;
typedef __bf16 bf16x8 __attribute__((ext_vector_type(8)));
typedef short  short8 __attribute__((ext_vector_type(8)));
typedef float  f32x4  __attribute__((ext_vector_type(4)));

#define BB 2
#define SS 2048
#define DD 2048
#define HH 16
#define HDIM 128

static __device__ __forceinline__ f32x4 mfma16(short8 a, short8 b, f32x4 c) {
    return __builtin_amdgcn_mfma_f32_16x16x32_bf16(
        __builtin_bit_cast(bf16x8, a), __builtin_bit_cast(bf16x8, b), c, 0, 0, 0);
}

static __device__ __forceinline__ u16 f2bf(float f) {
    union { float f; unsigned u; } v; v.f = f;
    unsigned r = v.u + 0x7fffu + ((v.u >> 16) & 1u);
    return (u16)(r >> 16);
}

static __device__ __forceinline__ uint4 pack8(float4 a, float4 b) {
    uint4 o;
    o.x = (unsigned)f2bf(a.x) | ((unsigned)f2bf(a.y) << 16);
    o.y = (unsigned)f2bf(a.z) | ((unsigned)f2bf(a.w) << 16);
    o.z = (unsigned)f2bf(b.x) | ((unsigned)f2bf(b.y) << 16);
    o.w = (unsigned)f2bf(b.z) | ((unsigned)f2bf(b.w) << 16);
    return o;
}

static __device__ __forceinline__ void gload_lds16(const u16* g, u16* l) {
    __builtin_amdgcn_global_load_lds(
        (const __attribute__((address_space(1))) unsigned int*)g,
        (__attribute__((address_space(3))) unsigned int*)l, 16, 0, 0);
}

// fp32 -> bf16 elementwise, 8 elems/thread, grid-stride
__global__ __launch_bounds__(256) void conv_bf16(
    const float* __restrict__ in, u16* __restrict__ out, int n8)
{
    const int stride = gridDim.x * blockDim.x;
    for (int i = blockIdx.x * blockDim.x + threadIdx.x; i < n8; i += stride) {
        const float4* s = (const float4*)in + (size_t)i * 2;
        float4 a = s[0], b = s[1];
        ((uint4*)out)[i] = pack8(a, b);
    }
}

// C[M][N] = A[M][K] @ W[N][K]^T + bias. A, W bf16; C bf16 or fp32.
// m97 structure: 128x128 tile, BK=32, linear LDS, global_load_lds width=16.
template<bool C_BF16>
__global__ __launch_bounds__(256) void gemm_bf16(
    const u16* __restrict__ A, const u16* __restrict__ Wb,
    const float* __restrict__ bias, void* __restrict__ Cp,
    int M, int N, int K)
{
    __shared__ u16 Al[128 * 32];
    __shared__ u16 Bl[128 * 32];

    const int tid = threadIdx.x;
    const int lane = tid & 63;
    const int lg = lane >> 4, li = lane & 15;
    const int wid = tid >> 6;
    const int brow = blockIdx.x * 128, bcol = blockIdx.y * 128;
    const int wm = wid >> 1, wn = wid & 1;

    const int srow = tid >> 2;          // staging row 0..63 (issue 0)
    const int scol = (tid & 3) * 8;     // staging col (elems)

    const f32x4 zero = {0.f, 0.f, 0.f, 0.f};
    f32x4 acc[4][4];
#pragma unroll
    for (int i = 0; i < 4; ++i)
#pragma unroll
        for (int j = 0; j < 4; ++j) acc[i][j] = zero;

    const u16* aptr = A  + (size_t)(brow + srow) * K + scol;
    const u16* bptr = Wb + (size_t)(bcol + srow) * K + scol;
    const size_t half = (size_t)64 * K;

    for (int kt = 0; kt < K; kt += 32) {
        gload_lds16(aptr + kt,        &Al[tid * 8]);
        gload_lds16(aptr + half + kt, &Al[2048 + tid * 8]);
        gload_lds16(bptr + kt,        &Bl[tid * 8]);
        gload_lds16(bptr + half + kt, &Bl[2048 + tid * 8]);
        __syncthreads();

        short8 af[4], bf[4];
#pragma unroll
        for (int mi = 0; mi < 4; ++mi)
            af[mi] = *(const short8*)(&Al[(wm * 64 + mi * 16 + li) * 32 + lg * 8]);
#pragma unroll
        for (int ni = 0; ni < 4; ++ni)
            bf[ni] = *(const short8*)(&Bl[(wn * 64 + ni * 16 + li) * 32 + lg * 8]);
#pragma unroll
        for (int mi = 0; mi < 4; ++mi)
#pragma unroll
            for (int ni = 0; ni < 4; ++ni)
                acc[mi][ni] = mfma16(af[mi], bf[ni], acc[mi][ni]);
        __syncthreads();
    }

    // epilogue: C layout col=lane&15, row=(lane>>4)*4+reg (m89-verified)
#pragma unroll
    for (int ni = 0; ni < 4; ++ni) {
        const int col = bcol + wn * 64 + ni * 16 + li;
        const float bv = bias[col];
#pragma unroll
        for (int mi = 0; mi < 4; ++mi) {
#pragma unroll
            for (int r = 0; r < 4; ++r) {
                const int row = brow + wm * 64 + mi * 16 + lg * 4 + r;
                const float v = acc[mi][ni][r] + bv;
                if (C_BF16) ((u16*)Cp)[(size_t)row * N + col] = f2bf(v);
                else        ((float*)Cp)[(size_t)row * N + col] = v;
            }
        }
    }
}

// Flash attention, causal. Q,K,V,O: bf16 [B*S][D], head h at cols h*128..h*128+127.
// Block: one (b, h, 64-row q-tile). 4 waves x 16 q-rows each. KV tile = 64.
__global__ __launch_bounds__(256) void flash_attn(
    const u16* __restrict__ Q, const u16* __restrict__ Kp,
    const u16* __restrict__ Vp, u16* __restrict__ O)
{
    constexpr int SK = 136;   // K_lds row stride (elems), 272B: b128 reads 2-way (free)
    constexpr int SV = 72;    // Vt row stride (elems), 144B
    constexpr int SP = 72;
    __shared__ u16 Kl[64 * SK];        // K tile [kv][d]
    __shared__ u16 Vt[HDIM * SV];      // V tile transposed [d][kv], kv chunk-XOR-swizzled
    __shared__ u16 Pl[4 * 16 * SP];    // per-wave P [16][64]

    const int tid = threadIdx.x;
    const int wid = tid >> 6, lane = tid & 63;
    const int lg = lane >> 4, li = lane & 15;
    const int qt = (int)gridDim.x - 1 - (int)blockIdx.x;  // heavy tiles launch first
    const int h = blockIdx.y, b = blockIdx.z;

    // fold 1/sqrt(128) and log2(e): softmax done in exp2 domain
    const float kscale = 0.08838834764831845f * 1.44269504088896f;

    short8 qf[4];
    {
        const u16* qp = Q + (size_t)(b * SS + qt * 64 + wid * 16 + li) * DD + h * HDIM + lg * 8;
#pragma unroll
        for (int s = 0; s < 4; ++s) qf[s] = *(const short8*)(qp + s * 32);
    }

    const f32x4 zero = {0.f, 0.f, 0.f, 0.f};
    float m_r[4], l_r[4];
    f32x4 accO[8];
#pragma unroll
    for (int r = 0; r < 4; ++r) { m_r[r] = -__builtin_inff(); l_r[r] = 0.f; }
#pragma unroll
    for (int d = 0; d < 8; ++d) accO[d] = zero;

    const int sr  = tid >> 2;          // kv row 0..63
    const int sc4 = (tid & 3) * 32;    // d chunk base

    for (int kt = 0; kt <= qt; ++kt) {
        // ---- stage K tile and V^T tile ----
        {
            const size_t base = (size_t)(b * SS + kt * 64 + sr) * DD + h * HDIM + sc4;
            const uint4* ks = (const uint4*)(Kp + base);
            uint4* kd = (uint4*)(&Kl[sr * SK + sc4]);
#pragma unroll
            for (int c = 0; c < 4; ++c) kd[c] = ks[c];
            const uint4* vs = (const uint4*)(Vp + base);
#pragma unroll
            for (int c = 0; c < 4; ++c) {
                uint4 u = vs[c];
                const int d0 = sc4 + c * 8;                 // d0 % 8 == 0
                const int x  = ((sr >> 3) ^ ((d0 >> 3) & 7)) << 3;
                const int boff = d0 * SV + x + (sr & 7);
                Vt[boff + 0 * SV] = (u16)(u.x);
                Vt[boff + 1 * SV] = (u16)(u.x >> 16);
                Vt[boff + 2 * SV] = (u16)(u.y);
                Vt[boff + 3 * SV] = (u16)(u.y >> 16);
                Vt[boff + 4 * SV] = (u16)(u.z);
                Vt[boff + 5 * SV] = (u16)(u.z >> 16);
                Vt[boff + 6 * SV] = (u16)(u.w);
                Vt[boff + 7 * SV] = (u16)(u.w >> 16);
            }
        }
        __syncthreads();

        // ---- scores: S[16 q][64 kv] per wave ----
        f32x4 accS[4] = {zero, zero, zero, zero};
#pragma unroll
        for (int s = 0; s < 4; ++s) {
#pragma unroll
            for (int nb = 0; nb < 4; ++nb) {
                short8 kf = *(const short8*)(&Kl[(nb * 16 + li) * SK + s * 32 + lg * 8]);
                accS[nb] = mfma16(qf[s], kf, accS[nb]);
            }
        }

        // ---- online softmax (exp2 domain) ----
        float p[4][4];
        float rmax[4];
#pragma unroll
        for (int r = 0; r < 4; ++r) rmax[r] = -__builtin_inff();
        const bool diag = (kt == qt);
#pragma unroll
        for (int nb = 0; nb < 4; ++nb)
#pragma unroll
            for (int r = 0; r < 4; ++r) {
                float t = accS[nb][r] * kscale;
                if (diag && (nb * 16 + li > wid * 16 + lg * 4 + r)) t = -__builtin_inff();
                p[nb][r] = t;
                rmax[r] = fmaxf(rmax[r], t);
            }
#pragma unroll
        for (int off = 1; off < 16; off <<= 1)
#pragma unroll
            for (int r = 0; r < 4; ++r)
                rmax[r] = fmaxf(rmax[r], __shfl_xor(rmax[r], off, 64));

        float sf[4], ls[4];
#pragma unroll
        for (int r = 0; r < 4; ++r) {
            const float mn = fmaxf(m_r[r], rmax[r]);   // finite: diag row always has col<=row
            sf[r] = exp2f(m_r[r] - mn);                // first iter: exp2(-inf)=0
            m_r[r] = mn;
            ls[r] = 0.f;
        }
#pragma unroll
        for (int nb = 0; nb < 4; ++nb)
#pragma unroll
            for (int r = 0; r < 4; ++r) {
                const float e = exp2f(p[nb][r] - m_r[r]);  // masked -> 0
                p[nb][r] = e;
                ls[r] += e;
            }
#pragma unroll
        for (int off = 1; off < 16; off <<= 1)
#pragma unroll
            for (int r = 0; r < 4; ++r)
                ls[r] += __shfl_xor(ls[r], off, 64);
#pragma unroll
        for (int r = 0; r < 4; ++r) l_r[r] = l_r[r] * sf[r] + ls[r];
#pragma unroll
        for (int d = 0; d < 8; ++d)
#pragma unroll
            for (int r = 0; r < 4; ++r) accO[d][r] *= sf[r];

        // ---- P -> LDS (per-wave region) ----
#pragma unroll
        for (int nb = 0; nb < 4; ++nb)
#pragma unroll
            for (int r = 0; r < 4; ++r)
                Pl[(wid * 16 + lg * 4 + r) * SP + nb * 16 + li] = f2bf(p[nb][r]);
        __syncthreads();

        // ---- PV: O[16 q][128 d] += P[16][64] @ V[64][128] ----
#pragma unroll
        for (int s2 = 0; s2 < 2; ++s2) {
            short8 pf = *(const short8*)(&Pl[(wid * 16 + li) * SP + s2 * 32 + lg * 8]);
#pragma unroll
            for (int db = 0; db < 8; ++db) {
                const int d  = db * 16 + li;
                const int cb = ((s2 * 4 + lg) ^ ((d >> 3) & 7)) << 3;
                short8 vf = *(const short8*)(&Vt[d * SV + cb]);
                accO[db] = mfma16(pf, vf, accO[db]);
            }
        }
        __syncthreads();
    }

    // ---- epilogue ----
#pragma unroll
    for (int db = 0; db < 8; ++db)
#pragma unroll
        for (int r = 0; r < 4; ++r) {
            const int row = qt * 64 + wid * 16 + lg * 4 + r;
            const float v = accO[db][r] / l_r[r];
            O[(size_t)(b * SS + row) * DD + h * HDIM + db * 16 + li] = f2bf(v);
        }
}

extern "C" void kernel_launch(void* const* d_in, const int* in_sizes, int n_in,
                              void* d_out, int out_size, void* d_ws, size_t ws_size,
                              hipStream_t stream)
{
    const float* queries = (const float*)d_in[0];
    const float* keys    = (const float*)d_in[1];
    const float* values  = (const float*)d_in[2];
    // d_in[3] = attention_mask: causal by construction, handled analytically
    const float* wq = (const float*)d_in[4];
    const float* bq = (const float*)d_in[5];
    const float* wk = (const float*)d_in[6];
    const float* bk = (const float*)d_in[7];
    const float* wv = (const float*)d_in[8];
    const float* bv = (const float*)d_in[9];
    const float* wo = (const float*)d_in[10];
    const float* bo = (const float*)d_in[11];

    const int M   = BB * SS;                    // 4096
    const int NMD = M * DD;                     // 8.4M
    const int NWW = DD * DD;                    // 4.2M

    u16* qb  = (u16*)d_ws;                      // converted inputs (bf16)
    u16* kb  = qb  + (size_t)NMD;
    u16* vb  = kb  + (size_t)NMD;
    u16* wqb = vb  + (size_t)NMD;               // converted weights (bf16)
    u16* wkb = wqb + (size_t)NWW;
    u16* wvb = wkb + (size_t)NWW;
    u16* wob = wvb + (size_t)NWW;
    u16* qw  = wob + (size_t)NWW;               // projection outputs (bf16)
    u16* kw  = qw  + (size_t)NMD;
    u16* vw  = kw  + (size_t)NMD;
    u16* aw  = vw  + (size_t)NMD;               // attention output (bf16)
    (void)in_sizes; (void)n_in; (void)out_size; (void)ws_size;

    dim3 blk(256);
    dim3 gridC(2048);
    dim3 gridG(M / 128, DD / 128);              // (32, 16)
    dim3 gridA(SS / 64, HH, BB);                // (32, 16, 2)

    conv_bf16<<<gridC, blk, 0, stream>>>(queries, qb, NMD / 8);
    conv_bf16<<<gridC, blk, 0, stream>>>(keys,    kb, NMD / 8);
    conv_bf16<<<gridC, blk, 0, stream>>>(values,  vb, NMD / 8);
    conv_bf16<<<gridC, blk, 0, stream>>>(wq, wqb, NWW / 8);
    conv_bf16<<<gridC, blk, 0, stream>>>(wk, wkb, NWW / 8);
    conv_bf16<<<gridC, blk, 0, stream>>>(wv, wvb, NWW / 8);
    conv_bf16<<<gridC, blk, 0, stream>>>(wo, wob, NWW / 8);

    gemm_bf16<true><<<gridG, blk, 0, stream>>>(qb, wqb, bq, qw, M, DD, DD);
    gemm_bf16<true><<<gridG, blk, 0, stream>>>(kb, wkb, bk, kw, M, DD, DD);
    gemm_bf16<true><<<gridG, blk, 0, stream>>>(vb, wvb, bv, vw, M, DD, DD);
    flash_attn<<<gridA, blk, 0, stream>>>(qw, kw, vw, aw);
    gemm_bf16<false><<<gridG, blk, 0, stream>>>(aw, wob, bo, (float*)d_out, M, DD, DD);
}

// Round 3
// 461.228 us; speedup vs baseline: 1.2071x; 1.0492x over previous
//
#include <hip/hip_runtime.h>
#include <hip/hip_bf16.h>

typedef unsigned short u16;
typedef __bf16 bf16x8 __attribute__((ext_vector_type(8)));
typedef short  short8 __attribute__((ext_vector_type(8)));
typedef float  f32x4  __attribute__((ext_vector_type(4)));

#define BB 2
#define SS 2048
#define DD 2048
#define HH 16
#define HDIM 128
#define MM (BB * SS)   // 4096 tokens

static __device__ __forceinline__ f32x4 mfma16(short8 a, short8 b, f32x4 c) {
    return __builtin_amdgcn_mfma_f32_16x16x32_bf16(
        __builtin_bit_cast(bf16x8, a), __builtin_bit_cast(bf16x8, b), c, 0, 0, 0);
}

static __device__ __forceinline__ u16 f2bf(float f) {
    union { float f; unsigned u; } v; v.f = f;
    unsigned r = v.u + 0x7fffu + ((v.u >> 16) & 1u);
    return (u16)(r >> 16);
}

static __device__ __forceinline__ uint4 pack8(float4 a, float4 b) {
    uint4 o;
    o.x = (unsigned)f2bf(a.x) | ((unsigned)f2bf(a.y) << 16);
    o.y = (unsigned)f2bf(a.z) | ((unsigned)f2bf(a.w) << 16);
    o.z = (unsigned)f2bf(b.x) | ((unsigned)f2bf(b.y) << 16);
    o.w = (unsigned)f2bf(b.z) | ((unsigned)f2bf(b.w) << 16);
    return o;
}

static __device__ __forceinline__ void gload_lds16(const u16* g, u16* l) {
    __builtin_amdgcn_global_load_lds(
        (const __attribute__((address_space(1))) unsigned int*)g,
        (__attribute__((address_space(3))) unsigned int*)l, 16, 0, 0);
}

// All 7 fp32->bf16 conversions fused: outputs are contiguous in ws.
__global__ __launch_bounds__(256) void conv_all(
    const float* __restrict__ q, const float* __restrict__ k, const float* __restrict__ v,
    const float* __restrict__ wq, const float* __restrict__ wk,
    const float* __restrict__ wv, const float* __restrict__ wo,
    u16* __restrict__ out)
{
    constexpr int n1 = MM * DD / 8;      // chunks per input tensor
    constexpr int nw = DD * DD / 8;      // chunks per weight
    constexpr int total = 3 * n1 + 4 * nw;
    const int stride = gridDim.x * blockDim.x;
    for (int i = blockIdx.x * blockDim.x + threadIdx.x; i < total; i += stride) {
        const float* s; int j = i;
        if (j < n1)            { s = q; }
        else if (j < 2 * n1)   { s = k;  j -= n1; }
        else if (j < 3 * n1)   { s = v;  j -= 2 * n1; }
        else {
            j -= 3 * n1;
            if (j < nw)        { s = wq; }
            else if (j < 2*nw) { s = wk; j -= nw; }
            else if (j < 3*nw) { s = wv; j -= 2 * nw; }
            else               { s = wo; j -= 3 * nw; }
        }
        const float4* sp = (const float4*)s + (size_t)j * 2;
        float4 a = sp[0], bb2 = sp[1];
        ((uint4*)out)[i] = pack8(a, bb2);
    }
}

// C[M][N] = A[M][K] @ W[N][K]^T + bias. A, W bf16.
// C_MODE: 0 = fp32 row-major, 1 = bf16 row-major, 2 = bf16 TRANSPOSED ([N][M])
template<int C_MODE>
__global__ __launch_bounds__(256) void gemm_bf16(
    const u16* __restrict__ A, const u16* __restrict__ Wb,
    const float* __restrict__ bias, void* __restrict__ Cp,
    int M, int N, int K)
{
    __shared__ u16 Al[128 * 32];
    __shared__ u16 Bl[128 * 32];
    __shared__ u16 Cl[C_MODE == 2 ? 128 * 132 : 1];

    const int tid = threadIdx.x;
    const int lane = tid & 63;
    const int lg = lane >> 4, li = lane & 15;
    const int wid = tid >> 6;
    const int brow = blockIdx.x * 128, bcol = blockIdx.y * 128;
    const int wm = wid >> 1, wn = wid & 1;

    const int srow = tid >> 2;
    const int scol = (tid & 3) * 8;

    const f32x4 zero = {0.f, 0.f, 0.f, 0.f};
    f32x4 acc[4][4];
#pragma unroll
    for (int i = 0; i < 4; ++i)
#pragma unroll
        for (int j = 0; j < 4; ++j) acc[i][j] = zero;

    const u16* aptr = A  + (size_t)(brow + srow) * K + scol;
    const u16* bptr = Wb + (size_t)(bcol + srow) * K + scol;
    const size_t half = (size_t)64 * K;

    for (int kt = 0; kt < K; kt += 32) {
        gload_lds16(aptr + kt,        &Al[tid * 8]);
        gload_lds16(aptr + half + kt, &Al[2048 + tid * 8]);
        gload_lds16(bptr + kt,        &Bl[tid * 8]);
        gload_lds16(bptr + half + kt, &Bl[2048 + tid * 8]);
        __syncthreads();

        short8 af[4], bf[4];
#pragma unroll
        for (int mi = 0; mi < 4; ++mi)
            af[mi] = *(const short8*)(&Al[(wm * 64 + mi * 16 + li) * 32 + lg * 8]);
#pragma unroll
        for (int ni = 0; ni < 4; ++ni)
            bf[ni] = *(const short8*)(&Bl[(wn * 64 + ni * 16 + li) * 32 + lg * 8]);
#pragma unroll
        for (int mi = 0; mi < 4; ++mi)
#pragma unroll
            for (int ni = 0; ni < 4; ++ni)
                acc[mi][ni] = mfma16(af[mi], bf[ni], acc[mi][ni]);
        __syncthreads();
    }

    if constexpr (C_MODE == 2) {
        // transposed epilogue: bounce acc through LDS, write C^T [N][M] coalesced
#pragma unroll
        for (int ni = 0; ni < 4; ++ni) {
            const int cc = wn * 64 + ni * 16 + li;            // local col (d)
            const float bv = bias[bcol + cc];
#pragma unroll
            for (int mi = 0; mi < 4; ++mi)
#pragma unroll
                for (int r = 0; r < 4; ++r) {
                    const int rr = wm * 64 + mi * 16 + lg * 4 + r;  // local row (token)
                    Cl[cc * 132 + rr] = f2bf(acc[mi][ni][r] + bv);
                }
        }
        __syncthreads();
        const int row = tid >> 1;                 // local d 0..127
        const int hcol = (tid & 1) * 64;          // token half
        u16* dst = (u16*)Cp + (size_t)(bcol + row) * M + brow + hcol;
#pragma unroll
        for (int c = 0; c < 8; ++c)
            *(short8*)(dst + c * 8) = *(const short8*)(&Cl[row * 132 + hcol + c * 8]);
    } else {
#pragma unroll
        for (int ni = 0; ni < 4; ++ni) {
            const int col = bcol + wn * 64 + ni * 16 + li;
            const float bv = bias[col];
#pragma unroll
            for (int mi = 0; mi < 4; ++mi) {
#pragma unroll
                for (int r = 0; r < 4; ++r) {
                    const int row = brow + wm * 64 + mi * 16 + lg * 4 + r;
                    const float v = acc[mi][ni][r] + bv;
                    if (C_MODE == 1) ((u16*)Cp)[(size_t)row * N + col] = f2bf(v);
                    else             ((float*)Cp)[(size_t)row * N + col] = v;
                }
            }
        }
    }
}

// Flash attention, causal. Q: bf16 [M][D] row-major; Vt: bf16 [D][M] (transposed).
// K: bf16 [M][D]. O: bf16 [M][D]. Block: one (b, h, 64-row q-tile), 4 waves.
// K/V^T staged via global_load_lds with XOR swizzle (byte ^= (row&7)<<4),
// pre-applied on the global source (rule 21). PV computed transposed.
__global__ __launch_bounds__(256) void flash_attn(
    const u16* __restrict__ Q, const u16* __restrict__ Kp,
    const u16* __restrict__ Vt, u16* __restrict__ O)
{
    constexpr int SP = 72;
    __shared__ u16 Kl[64 * 128];     // K tile [kv][128 d], swizzled
    __shared__ u16 Vl[128 * 64];     // V^T tile [d][64 kv], swizzled
    __shared__ u16 Pl[4 * 16 * SP];  // per-wave P [16 q][64 kv]

    const int tid = threadIdx.x;
    const int wid = tid >> 6, lane = tid & 63;
    const int lg = lane >> 4, li = lane & 15;
    const int qt = (int)gridDim.x - 1 - (int)blockIdx.x;  // heavy tiles first
    const int h = blockIdx.y, b = blockIdx.z;

    const float kscale = 0.08838834764831845f * 1.44269504088896f;

    short8 qf[4];
    {
        const u16* qp = Q + (size_t)(b * SS + qt * 64 + wid * 16 + li) * DD + h * HDIM + lg * 8;
#pragma unroll
        for (int s = 0; s < 4; ++s) qf[s] = *(const short8*)(qp + s * 32);
    }

    const f32x4 zero = {0.f, 0.f, 0.f, 0.f};
    float m_r[4], l_r[4];
    f32x4 accO[8];                    // O^T: reg r -> d = mb*16+lg*4+r, col -> q = li
#pragma unroll
    for (int r = 0; r < 4; ++r) { m_r[r] = -__builtin_inff(); l_r[r] = 0.f; }
#pragma unroll
    for (int d = 0; d < 8; ++d) accO[d] = zero;

    for (int kt = 0; kt <= qt; ++kt) {
        // ---- stage K [64][128] and V^T [128][64] via global_load_lds ----
#pragma unroll
        for (int i = 0; i < 4; ++i) {
            const int C = i * 256 + tid;
            const int rK = C >> 4, wK = C & 15;
            const int bK = (wK * 16) ^ ((rK & 7) << 4);
            gload_lds16(Kp + (size_t)(b * SS + kt * 64 + rK) * DD + h * HDIM + (bK >> 1),
                        &Kl[C * 8]);
            const int rV = C >> 3, wV = C & 7;
            const int bV = (wV * 16) ^ ((rV & 7) << 4);
            gload_lds16(Vt + (size_t)(h * HDIM + rV) * MM + b * SS + kt * 64 + (bV >> 1),
                        &Vl[C * 8]);
        }
        __syncthreads();

        // ---- scores: S[16 q][64 kv] per wave ----
        f32x4 accS[4] = {zero, zero, zero, zero};
#pragma unroll
        for (int s = 0; s < 4; ++s) {
#pragma unroll
            for (int nb = 0; nb < 4; ++nb) {
                const int R = nb * 16 + li;
                const int e = ((s * 64 + lg * 16) ^ ((R & 7) << 4)) >> 1;
                short8 kf = *(const short8*)(&Kl[R * 128 + e]);
                accS[nb] = mfma16(qf[s], kf, accS[nb]);
            }
        }

        // ---- online softmax (exp2 domain) ----
        float p[4][4];
        float rmax[4];
#pragma unroll
        for (int r = 0; r < 4; ++r) rmax[r] = -__builtin_inff();
        const bool diag = (kt == qt);
#pragma unroll
        for (int nb = 0; nb < 4; ++nb)
#pragma unroll
            for (int r = 0; r < 4; ++r) {
                float t = accS[nb][r] * kscale;
                if (diag && (nb * 16 + li > wid * 16 + lg * 4 + r)) t = -__builtin_inff();
                p[nb][r] = t;
                rmax[r] = fmaxf(rmax[r], t);
            }
#pragma unroll
        for (int off = 1; off < 16; off <<= 1)
#pragma unroll
            for (int r = 0; r < 4; ++r)
                rmax[r] = fmaxf(rmax[r], __shfl_xor(rmax[r], off, 64));

        float sf[4], ls[4];
#pragma unroll
        for (int r = 0; r < 4; ++r) {
            const float mn = fmaxf(m_r[r], rmax[r]);
            sf[r] = exp2f(m_r[r] - mn);
            m_r[r] = mn;
            ls[r] = 0.f;
        }
#pragma unroll
        for (int nb = 0; nb < 4; ++nb)
#pragma unroll
            for (int r = 0; r < 4; ++r) {
                const float e = exp2f(p[nb][r] - m_r[r]);
                p[nb][r] = e;
                ls[r] += e;
            }
#pragma unroll
        for (int off = 1; off < 16; off <<= 1)
#pragma unroll
            for (int r = 0; r < 4; ++r)
                ls[r] += __shfl_xor(ls[r], off, 64);
#pragma unroll
        for (int r = 0; r < 4; ++r) l_r[r] = l_r[r] * sf[r] + ls[r];

        // broadcast sf for row q=li (value lives in lanes lg==li>>2, reg li&3)
        {
            const int src = (li >> 2) * 16;
            const float s0 = __shfl(sf[0], src), s1 = __shfl(sf[1], src);
            const float s2 = __shfl(sf[2], src), s3 = __shfl(sf[3], src);
            const float a01 = (li & 1) ? s1 : s0;
            const float a23 = (li & 1) ? s3 : s2;
            const float sfq = (li & 2) ? a23 : a01;
#pragma unroll
            for (int mb = 0; mb < 8; ++mb)
#pragma unroll
                for (int r = 0; r < 4; ++r) accO[mb][r] *= sfq;
        }

        // ---- P -> LDS (per-wave region; intra-wave producer/consumer) ----
#pragma unroll
        for (int nb = 0; nb < 4; ++nb)
#pragma unroll
            for (int r = 0; r < 4; ++r)
                Pl[(wid * 16 + lg * 4 + r) * SP + nb * 16 + li] = f2bf(p[nb][r]);

        // ---- PV transposed: O^T[128 d][16 q] += V^T[128][64] @ P^T[64][16] ----
#pragma unroll
        for (int s2 = 0; s2 < 2; ++s2) {
            short8 pf = *(const short8*)(&Pl[(wid * 16 + li) * SP + s2 * 32 + lg * 8]);
#pragma unroll
            for (int mb = 0; mb < 8; ++mb) {
                const int R2 = mb * 16 + li;
                const int e2 = ((s2 * 64 + lg * 16) ^ ((R2 & 7) << 4)) >> 1;
                short8 vf = *(const short8*)(&Vl[R2 * 64 + e2]);
                accO[mb] = mfma16(vf, pf, accO[mb]);
            }
        }
        __syncthreads();
    }

    // ---- epilogue: un-transpose via per-wave LDS bounce (reuse Kl) ----
    {
        const int src = (li >> 2) * 16;
        const float l0 = __shfl(l_r[0], src), l1 = __shfl(l_r[1], src);
        const float l2 = __shfl(l_r[2], src), l3 = __shfl(l_r[3], src);
        const float a01 = (li & 1) ? l1 : l0;
        const float a23 = (li & 1) ? l3 : l2;
        const float linv = 1.f / ((li & 2) ? a23 : a01);

        u16* Wl = Kl + wid * 2048;       // 16 rows x 128 d per wave
#pragma unroll
        for (int mb = 0; mb < 8; ++mb)
#pragma unroll
            for (int r = 0; r < 4; ++r) {
                const int d = mb * 16 + lg * 4 + r;
                Wl[li * 128 + (d ^ ((li & 7) << 4))] = f2bf(accO[mb][r] * linv);
            }
        const int q = lane >> 2;
        const int d0 = (lane & 3) * 32;
        u16* op = O + (size_t)(b * SS + qt * 64 + wid * 16 + q) * DD + h * HDIM + d0;
#pragma unroll
        for (int c = 0; c < 4; ++c) {
            short8 vv = *(const short8*)(&Wl[q * 128 + ((d0 + c * 8) ^ ((q & 7) << 4))]);
            *(short8*)(op + c * 8) = vv;
        }
    }
}

extern "C" void kernel_launch(void* const* d_in, const int* in_sizes, int n_in,
                              void* d_out, int out_size, void* d_ws, size_t ws_size,
                              hipStream_t stream)
{
    const float* queries = (const float*)d_in[0];
    const float* keys    = (const float*)d_in[1];
    const float* values  = (const float*)d_in[2];
    // d_in[3] = attention_mask: causal by construction
    const float* wq = (const float*)d_in[4];
    const float* bq = (const float*)d_in[5];
    const float* wk = (const float*)d_in[6];
    const float* bk = (const float*)d_in[7];
    const float* wv = (const float*)d_in[8];
    const float* bv = (const float*)d_in[9];
    const float* wo = (const float*)d_in[10];
    const float* bo = (const float*)d_in[11];

    const int M   = MM;
    const int NMD = M * DD;
    const int NWW = DD * DD;

    u16* qb  = (u16*)d_ws;                      // converted inputs (bf16)
    u16* kb  = qb  + (size_t)NMD;
    u16* vb  = kb  + (size_t)NMD;
    u16* wqb = vb  + (size_t)NMD;               // converted weights (bf16)
    u16* wkb = wqb + (size_t)NWW;
    u16* wvb = wkb + (size_t)NWW;
    u16* wob = wvb + (size_t)NWW;
    u16* qw  = wob + (size_t)NWW;               // q projection (bf16 [M][D])
    u16* kw  = qw  + (size_t)NMD;               // k projection (bf16 [M][D])
    u16* vtw = kw  + (size_t)NMD;               // v projection TRANSPOSED ([D][M])
    u16* aw  = vtw + (size_t)NMD;               // attention output (bf16 [M][D])
    (void)in_sizes; (void)n_in; (void)out_size; (void)ws_size;

    dim3 blk(256);
    dim3 gridC(2048);
    dim3 gridG(M / 128, DD / 128);              // (32, 16)
    dim3 gridA(SS / 64, HH, BB);                // (32, 16, 2)

    conv_all<<<gridC, blk, 0, stream>>>(queries, keys, values, wq, wk, wv, wo, qb);

    gemm_bf16<1><<<gridG, blk, 0, stream>>>(qb, wqb, bq, qw,  M, DD, DD);
    gemm_bf16<1><<<gridG, blk, 0, stream>>>(kb, wkb, bk, kw,  M, DD, DD);
    gemm_bf16<2><<<gridG, blk, 0, stream>>>(vb, wvb, bv, vtw, M, DD, DD);
    flash_attn<<<gridA, blk, 0, stream>>>(qw, kw, vtw, aw);
    gemm_bf16<0><<<gridG, blk, 0, stream>>>(aw, wob, bo, (float*)d_out, M, DD, DD);
}

// Round 4
// 396.924 us; speedup vs baseline: 1.4027x; 1.1620x over previous
//
#include <hip/hip_runtime.h>
#include <hip/hip_bf16.h>

typedef unsigned short u16;
typedef __bf16 bf16x8 __attribute__((ext_vector_type(8)));
typedef short  short8 __attribute__((ext_vector_type(8)));
typedef float  f32x4  __attribute__((ext_vector_type(4)));

#define BB 2
#define SS 2048
#define DD 2048
#define HH 16
#define HDIM 128
#define MM (BB * SS)   // 4096 tokens
// 1/sqrt(128) * log2(e), folded into wq/bq at conversion
#define KSCALE 0.12752039505554602f

static __device__ __forceinline__ f32x4 mfma16(short8 a, short8 b, f32x4 c) {
    return __builtin_amdgcn_mfma_f32_16x16x32_bf16(
        __builtin_bit_cast(bf16x8, a), __builtin_bit_cast(bf16x8, b), c, 0, 0, 0);
}

static __device__ __forceinline__ u16 f2bf(float f) {
    union { float f; unsigned u; } v; v.f = f;
    unsigned r = v.u + 0x7fffu + ((v.u >> 16) & 1u);
    return (u16)(r >> 16);
}

static __device__ __forceinline__ uint4 pack8(float4 a, float4 b) {
    uint4 o;
    o.x = (unsigned)f2bf(a.x) | ((unsigned)f2bf(a.y) << 16);
    o.y = (unsigned)f2bf(a.z) | ((unsigned)f2bf(a.w) << 16);
    o.z = (unsigned)f2bf(b.x) | ((unsigned)f2bf(b.y) << 16);
    o.w = (unsigned)f2bf(b.z) | ((unsigned)f2bf(b.w) << 16);
    return o;
}

static __device__ __forceinline__ void gload_lds16(const u16* g, u16* l) {
    __builtin_amdgcn_global_load_lds(
        (const __attribute__((address_space(1))) unsigned int*)g,
        (__attribute__((address_space(3))) unsigned int*)l, 16, 0, 0);
}

// All 7 fp32->bf16 conversions fused. wq segment is pre-scaled by KSCALE.
__global__ __launch_bounds__(256) void conv_all(
    const float* __restrict__ q, const float* __restrict__ k, const float* __restrict__ v,
    const float* __restrict__ wq, const float* __restrict__ wk,
    const float* __restrict__ wv, const float* __restrict__ wo,
    u16* __restrict__ out)
{
    constexpr int n1 = MM * DD / 8;
    constexpr int nw = DD * DD / 8;
    constexpr int total = 3 * n1 + 4 * nw;
    const int stride = gridDim.x * blockDim.x;
    for (int i = blockIdx.x * blockDim.x + threadIdx.x; i < total; i += stride) {
        const float* s; int j = i; float sc = 1.f;
        if (j < n1)            { s = q; }
        else if (j < 2 * n1)   { s = k;  j -= n1; }
        else if (j < 3 * n1)   { s = v;  j -= 2 * n1; }
        else {
            j -= 3 * n1;
            if (j < nw)        { s = wq; sc = KSCALE; }
            else if (j < 2*nw) { s = wk; j -= nw; }
            else if (j < 3*nw) { s = wv; j -= 2 * nw; }
            else               { s = wo; j -= 3 * nw; }
        }
        const float4* sp = (const float4*)s + (size_t)j * 2;
        float4 a = sp[0], bb2 = sp[1];
        a.x *= sc; a.y *= sc; a.z *= sc; a.w *= sc;
        bb2.x *= sc; bb2.y *= sc; bb2.z *= sc; bb2.w *= sc;
        ((uint4*)out)[i] = pack8(a, bb2);
    }
}

// C[M][N] = A[M][K] @ W[N][K]^T + bias*bscale. A, W bf16.
// C_MODE: 0 = fp32 row-major, 1 = bf16 row-major, 2 = bf16 TRANSPOSED ([N][M])
template<int C_MODE>
__global__ __launch_bounds__(256) void gemm_bf16(
    const u16* __restrict__ A, const u16* __restrict__ Wb,
    const float* __restrict__ bias, void* __restrict__ Cp,
    int M, int N, int K, float bscale)
{
    __shared__ u16 Al[128 * 32];
    __shared__ u16 Bl[128 * 32];
    __shared__ u16 Cl[C_MODE == 2 ? 128 * 132 : 1];

    const int tid = threadIdx.x;
    const int lane = tid & 63;
    const int lg = lane >> 4, li = lane & 15;
    const int wid = tid >> 6;
    const int brow = blockIdx.x * 128, bcol = blockIdx.y * 128;
    const int wm = wid >> 1, wn = wid & 1;

    const int srow = tid >> 2;
    const int scol = (tid & 3) * 8;

    const f32x4 zero = {0.f, 0.f, 0.f, 0.f};
    f32x4 acc[4][4];
#pragma unroll
    for (int i = 0; i < 4; ++i)
#pragma unroll
        for (int j = 0; j < 4; ++j) acc[i][j] = zero;

    const u16* aptr = A  + (size_t)(brow + srow) * K + scol;
    const u16* bptr = Wb + (size_t)(bcol + srow) * K + scol;
    const size_t half = (size_t)64 * K;

    for (int kt = 0; kt < K; kt += 32) {
        gload_lds16(aptr + kt,        &Al[tid * 8]);
        gload_lds16(aptr + half + kt, &Al[2048 + tid * 8]);
        gload_lds16(bptr + kt,        &Bl[tid * 8]);
        gload_lds16(bptr + half + kt, &Bl[2048 + tid * 8]);
        __syncthreads();

        short8 af[4], bf[4];
#pragma unroll
        for (int mi = 0; mi < 4; ++mi)
            af[mi] = *(const short8*)(&Al[(wm * 64 + mi * 16 + li) * 32 + lg * 8]);
#pragma unroll
        for (int ni = 0; ni < 4; ++ni)
            bf[ni] = *(const short8*)(&Bl[(wn * 64 + ni * 16 + li) * 32 + lg * 8]);
#pragma unroll
        for (int mi = 0; mi < 4; ++mi)
#pragma unroll
            for (int ni = 0; ni < 4; ++ni)
                acc[mi][ni] = mfma16(af[mi], bf[ni], acc[mi][ni]);
        __syncthreads();
    }

    if constexpr (C_MODE == 2) {
#pragma unroll
        for (int ni = 0; ni < 4; ++ni) {
            const int cc = wn * 64 + ni * 16 + li;
            const float bv = bias[bcol + cc] * bscale;
#pragma unroll
            for (int mi = 0; mi < 4; ++mi)
#pragma unroll
                for (int r = 0; r < 4; ++r) {
                    const int rr = wm * 64 + mi * 16 + lg * 4 + r;
                    Cl[cc * 132 + rr] = f2bf(acc[mi][ni][r] + bv);
                }
        }
        __syncthreads();
        const int row = tid >> 1;
        const int hcol = (tid & 1) * 64;
        u16* dst = (u16*)Cp + (size_t)(bcol + row) * M + brow + hcol;
#pragma unroll
        for (int c = 0; c < 8; ++c)
            *(short8*)(dst + c * 8) = *(const short8*)(&Cl[row * 132 + hcol + c * 8]);
    } else {
#pragma unroll
        for (int ni = 0; ni < 4; ++ni) {
            const int col = bcol + wn * 64 + ni * 16 + li;
            const float bv = bias[col] * bscale;
#pragma unroll
            for (int mi = 0; mi < 4; ++mi) {
#pragma unroll
                for (int r = 0; r < 4; ++r) {
                    const int row = brow + wm * 64 + mi * 16 + lg * 4 + r;
                    const float v = acc[mi][ni][r] + bv;
                    if (C_MODE == 1) ((u16*)Cp)[(size_t)row * N + col] = f2bf(v);
                    else             ((float*)Cp)[(size_t)row * N + col] = v;
                }
            }
        }
    }
}

// Flash attention, causal, swapped-QK^T (S^T = K·Q^T so q is lane-local).
// Q already folded with KSCALE (via wq/bq). Vt: bf16 [D][M] transposed.
// Block: one (b, h, 64-row q-tile), 4 waves x 16 q each. KV tile 64.
__global__ __launch_bounds__(256) void flash_attn(
    const u16* __restrict__ Q, const u16* __restrict__ Kp,
    const u16* __restrict__ Vt, u16* __restrict__ O)
{
    constexpr int SP = 72;
    __shared__ u16 Kl[64 * 128];     // K tile [kv][128 d], XOR-swizzled
    __shared__ u16 Vl[128 * 64];     // V^T tile [d][64 kv], XOR-swizzled
    __shared__ u16 Pl[4 * 16 * SP];  // per-wave P [16 q][64 kv]

    const int tid = threadIdx.x;
    const int wid = tid >> 6, lane = tid & 63;
    const int lg = lane >> 4, li = lane & 15;
    const int qt = (int)gridDim.x - 1 - (int)blockIdx.x;  // heavy tiles first
    const int h = blockIdx.y, b = blockIdx.z;
    const int qloc = wid * 16 + li;                       // q within 64-tile

    short8 qf[4];
    {
        const u16* qp = Q + (size_t)(b * SS + qt * 64 + qloc) * DD + h * HDIM + lg * 8;
#pragma unroll
        for (int s = 0; s < 4; ++s) qf[s] = *(const short8*)(qp + s * 32);
    }

    const f32x4 zero = {0.f, 0.f, 0.f, 0.f};
    float m_r = -__builtin_inff(), l_r = 0.f;
    f32x4 accO[8];                    // O^T: reg r -> d = mb*16+lg*4+r, col -> q = li
#pragma unroll
    for (int d = 0; d < 8; ++d) accO[d] = zero;

    for (int kt = 0; kt <= qt; ++kt) {
        // ---- stage K [64][128] and V^T [128][64] via global_load_lds ----
#pragma unroll
        for (int i = 0; i < 4; ++i) {
            const int C = i * 256 + tid;
            const int rK = C >> 4, wK = C & 15;
            const int bK = (wK * 16) ^ ((rK & 7) << 4);
            gload_lds16(Kp + (size_t)(b * SS + kt * 64 + rK) * DD + h * HDIM + (bK >> 1),
                        &Kl[C * 8]);
            const int rV = C >> 3, wV = C & 7;
            const int bV = (wV * 16) ^ ((rV & 7) << 4);
            gload_lds16(Vt + (size_t)(h * HDIM + rV) * MM + b * SS + kt * 64 + (bV >> 1),
                        &Vl[C * 8]);
        }
        __syncthreads();

        // ---- scores TRANSPOSED: S^T[64 kv][16 q], A=K, B=Q ----
        f32x4 accS[4] = {zero, zero, zero, zero};
        __builtin_amdgcn_s_setprio(1);
#pragma unroll
        for (int s = 0; s < 4; ++s) {
#pragma unroll
            for (int nb = 0; nb < 4; ++nb) {
                const int R = nb * 16 + li;
                const int e = ((s * 64 + lg * 16) ^ ((R & 7) << 4)) >> 1;
                short8 kf = *(const short8*)(&Kl[R * 128 + e]);
                accS[nb] = mfma16(kf, qf[s], accS[nb]);   // swapped: A=K, B=Q
            }
        }
        __builtin_amdgcn_s_setprio(0);

        // ---- online softmax, per-lane (q = li), exp2 domain ----
        float p[4][4];
        float rmax = -__builtin_inff();
        const bool diag = (kt == qt);
#pragma unroll
        for (int nb = 0; nb < 4; ++nb)
#pragma unroll
            for (int r = 0; r < 4; ++r) {
                float t = accS[nb][r];                    // kv = nb*16+lg*4+r
                if (diag && (nb * 16 + lg * 4 + r > qloc)) t = -__builtin_inff();
                p[nb][r] = t;
                rmax = fmaxf(rmax, t);
            }
        rmax = fmaxf(rmax, __shfl_xor(rmax, 16, 64));
        rmax = fmaxf(rmax, __shfl_xor(rmax, 32, 64));

        // defer-max (T13): skip rescale while max growth is small
        if (!__all(rmax - m_r <= 11.5f)) {
            const float mn = fmaxf(m_r, rmax);
            const float sf = exp2f(m_r - mn);
            m_r = mn;
            l_r *= sf;
#pragma unroll
            for (int mb = 0; mb < 8; ++mb)
#pragma unroll
                for (int r = 0; r < 4; ++r) accO[mb][r] *= sf;
        }

        float ls = 0.f;
#pragma unroll
        for (int nb = 0; nb < 4; ++nb)
#pragma unroll
            for (int r = 0; r < 4; ++r) {
                const float e = exp2f(p[nb][r] - m_r);
                p[nb][r] = e;
                ls += e;
            }
        ls += __shfl_xor(ls, 16, 64);
        ls += __shfl_xor(ls, 32, 64);
        l_r += ls;

        // ---- P^T -> row-major P[q][kv] in LDS (per-wave region) ----
#pragma unroll
        for (int nb = 0; nb < 4; ++nb)
#pragma unroll
            for (int r = 0; r < 4; ++r)
                Pl[(wid * 16 + li) * SP + nb * 16 + lg * 4 + r] = f2bf(p[nb][r]);

        // ---- PV transposed: O^T[128 d][16 q] += V^T[128][64] @ P^T[64][16] ----
        __builtin_amdgcn_s_setprio(1);
#pragma unroll
        for (int s2 = 0; s2 < 2; ++s2) {
            short8 pf = *(const short8*)(&Pl[(wid * 16 + li) * SP + s2 * 32 + lg * 8]);
#pragma unroll
            for (int mb = 0; mb < 8; ++mb) {
                const int R2 = mb * 16 + li;
                const int e2 = ((s2 * 64 + lg * 16) ^ ((R2 & 7) << 4)) >> 1;
                short8 vf = *(const short8*)(&Vl[R2 * 64 + e2]);
                accO[mb] = mfma16(vf, pf, accO[mb]);
            }
        }
        __builtin_amdgcn_s_setprio(0);
        __syncthreads();
    }

    // ---- epilogue: un-transpose via per-wave LDS bounce (reuse Kl) ----
    {
        const float linv = 1.f / l_r;                 // per-lane: q = li
        u16* Wl = Kl + wid * 2048;                    // 16 q x 128 d per wave
#pragma unroll
        for (int mb = 0; mb < 8; ++mb)
#pragma unroll
            for (int r = 0; r < 4; ++r) {
                const int d = mb * 16 + lg * 4 + r;
                Wl[li * 128 + (d ^ ((li & 7) << 4))] = f2bf(accO[mb][r] * linv);
            }
        const int q = lane >> 2;
        const int d0 = (lane & 3) * 32;
        u16* op = O + (size_t)(b * SS + qt * 64 + wid * 16 + q) * DD + h * HDIM + d0;
#pragma unroll
        for (int c = 0; c < 4; ++c) {
            short8 vv = *(const short8*)(&Wl[q * 128 + ((d0 + c * 8) ^ ((q & 7) << 4))]);
            *(short8*)(op + c * 8) = vv;
        }
    }
}

extern "C" void kernel_launch(void* const* d_in, const int* in_sizes, int n_in,
                              void* d_out, int out_size, void* d_ws, size_t ws_size,
                              hipStream_t stream)
{
    const float* queries = (const float*)d_in[0];
    const float* keys    = (const float*)d_in[1];
    const float* values  = (const float*)d_in[2];
    // d_in[3] = attention_mask: causal by construction
    const float* wq = (const float*)d_in[4];
    const float* bq = (const float*)d_in[5];
    const float* wk = (const float*)d_in[6];
    const float* bk = (const float*)d_in[7];
    const float* wv = (const float*)d_in[8];
    const float* bv = (const float*)d_in[9];
    const float* wo = (const float*)d_in[10];
    const float* bo = (const float*)d_in[11];

    const int M   = MM;
    const int NMD = M * DD;
    const int NWW = DD * DD;

    u16* qb  = (u16*)d_ws;
    u16* kb  = qb  + (size_t)NMD;
    u16* vb  = kb  + (size_t)NMD;
    u16* wqb = vb  + (size_t)NMD;               // pre-scaled by KSCALE
    u16* wkb = wqb + (size_t)NWW;
    u16* wvb = wkb + (size_t)NWW;
    u16* wob = wvb + (size_t)NWW;
    u16* qw  = wob + (size_t)NWW;               // q proj (bf16 [M][D], KSCALE folded)
    u16* kw  = qw  + (size_t)NMD;               // k proj (bf16 [M][D])
    u16* vtw = kw  + (size_t)NMD;               // v proj TRANSPOSED ([D][M])
    u16* aw  = vtw + (size_t)NMD;               // attention output (bf16 [M][D])
    (void)in_sizes; (void)n_in; (void)out_size; (void)ws_size;

    dim3 blk(256);
    dim3 gridC(2048);
    dim3 gridG(M / 128, DD / 128);              // (32, 16)
    dim3 gridA(SS / 64, HH, BB);                // (32, 16, 2)

    conv_all<<<gridC, blk, 0, stream>>>(queries, keys, values, wq, wk, wv, wo, qb);

    gemm_bf16<1><<<gridG, blk, 0, stream>>>(qb, wqb, bq, qw,  M, DD, DD, KSCALE);
    gemm_bf16<1><<<gridG, blk, 0, stream>>>(kb, wkb, bk, kw,  M, DD, DD, 1.f);
    gemm_bf16<2><<<gridG, blk, 0, stream>>>(vb, wvb, bv, vtw, M, DD, DD, 1.f);
    flash_attn<<<gridA, blk, 0, stream>>>(qw, kw, vtw, aw);
    gemm_bf16<0><<<gridG, blk, 0, stream>>>(aw, wob, bo, (float*)d_out, M, DD, DD, 1.f);
}

// Round 5
// 396.906 us; speedup vs baseline: 1.4027x; 1.0000x over previous
//
#include <hip/hip_runtime.h>
#include <hip/hip_bf16.h>

typedef unsigned short u16;
typedef __bf16 bf16x8 __attribute__((ext_vector_type(8)));
typedef short  short8 __attribute__((ext_vector_type(8)));
typedef float  f32x4  __attribute__((ext_vector_type(4)));

#define BB 2
#define SS 2048
#define DD 2048
#define HH 16
#define HDIM 128
#define MM (BB * SS)   // 4096 tokens
// 1/sqrt(128) * log2(e), folded into wq/bq at conversion
#define KSCALE 0.12752039505554602f

static __device__ __forceinline__ f32x4 mfma16(short8 a, short8 b, f32x4 c) {
    return __builtin_amdgcn_mfma_f32_16x16x32_bf16(
        __builtin_bit_cast(bf16x8, a), __builtin_bit_cast(bf16x8, b), c, 0, 0, 0);
}

static __device__ __forceinline__ u16 f2bf(float f) {
    union { float f; unsigned u; } v; v.f = f;
    unsigned r = v.u + 0x7fffu + ((v.u >> 16) & 1u);
    return (u16)(r >> 16);
}

static __device__ __forceinline__ uint4 pack8(float4 a, float4 b) {
    uint4 o;
    o.x = (unsigned)f2bf(a.x) | ((unsigned)f2bf(a.y) << 16);
    o.y = (unsigned)f2bf(a.z) | ((unsigned)f2bf(a.w) << 16);
    o.z = (unsigned)f2bf(b.x) | ((unsigned)f2bf(b.y) << 16);
    o.w = (unsigned)f2bf(b.z) | ((unsigned)f2bf(b.w) << 16);
    return o;
}

static __device__ __forceinline__ void gload_lds16(const u16* g, u16* l) {
    __builtin_amdgcn_global_load_lds(
        (const __attribute__((address_space(1))) unsigned int*)g,
        (__attribute__((address_space(3))) unsigned int*)l, 16, 0, 0);
}

// All 7 fp32->bf16 conversions fused. wq segment is pre-scaled by KSCALE.
__global__ __launch_bounds__(256) void conv_all(
    const float* __restrict__ q, const float* __restrict__ k, const float* __restrict__ v,
    const float* __restrict__ wq, const float* __restrict__ wk,
    const float* __restrict__ wv, const float* __restrict__ wo,
    u16* __restrict__ out)
{
    constexpr int n1 = MM * DD / 8;
    constexpr int nw = DD * DD / 8;
    constexpr int total = 3 * n1 + 4 * nw;
    const int stride = gridDim.x * blockDim.x;
    for (int i = blockIdx.x * blockDim.x + threadIdx.x; i < total; i += stride) {
        const float* s; int j = i; float sc = 1.f;
        if (j < n1)            { s = q; }
        else if (j < 2 * n1)   { s = k;  j -= n1; }
        else if (j < 3 * n1)   { s = v;  j -= 2 * n1; }
        else {
            j -= 3 * n1;
            if (j < nw)        { s = wq; sc = KSCALE; }
            else if (j < 2*nw) { s = wk; j -= nw; }
            else if (j < 3*nw) { s = wv; j -= 2 * nw; }
            else               { s = wo; j -= 3 * nw; }
        }
        const float4* sp = (const float4*)s + (size_t)j * 2;
        float4 a = sp[0], bb2 = sp[1];
        a.x *= sc; a.y *= sc; a.z *= sc; a.w *= sc;
        bb2.x *= sc; bb2.y *= sc; bb2.z *= sc; bb2.w *= sc;
        ((uint4*)out)[i] = pack8(a, bb2);
    }
}

// C[M][N] = A[M][K] @ W[N][K]^T + bias*bscale. A, W bf16.
// C_MODE: 0 = fp32 row-major, 1 = bf16 row-major, 2 = bf16 TRANSPOSED ([N][M])
template<int C_MODE>
__global__ __launch_bounds__(256) void gemm_bf16(
    const u16* __restrict__ A, const u16* __restrict__ Wb,
    const float* __restrict__ bias, void* __restrict__ Cp,
    int M, int N, int K, float bscale)
{
    __shared__ u16 Al[128 * 32];
    __shared__ u16 Bl[128 * 32];
    __shared__ u16 Cl[C_MODE == 2 ? 128 * 132 : 1];

    const int tid = threadIdx.x;
    const int lane = tid & 63;
    const int lg = lane >> 4, li = lane & 15;
    const int wid = tid >> 6;
    const int brow = blockIdx.x * 128, bcol = blockIdx.y * 128;
    const int wm = wid >> 1, wn = wid & 1;

    const int srow = tid >> 2;
    const int scol = (tid & 3) * 8;

    const f32x4 zero = {0.f, 0.f, 0.f, 0.f};
    f32x4 acc[4][4];
#pragma unroll
    for (int i = 0; i < 4; ++i)
#pragma unroll
        for (int j = 0; j < 4; ++j) acc[i][j] = zero;

    const u16* aptr = A  + (size_t)(brow + srow) * K + scol;
    const u16* bptr = Wb + (size_t)(bcol + srow) * K + scol;
    const size_t half = (size_t)64 * K;

    for (int kt = 0; kt < K; kt += 32) {
        gload_lds16(aptr + kt,        &Al[tid * 8]);
        gload_lds16(aptr + half + kt, &Al[2048 + tid * 8]);
        gload_lds16(bptr + kt,        &Bl[tid * 8]);
        gload_lds16(bptr + half + kt, &Bl[2048 + tid * 8]);
        __syncthreads();

        short8 af[4], bf[4];
#pragma unroll
        for (int mi = 0; mi < 4; ++mi)
            af[mi] = *(const short8*)(&Al[(wm * 64 + mi * 16 + li) * 32 + lg * 8]);
#pragma unroll
        for (int ni = 0; ni < 4; ++ni)
            bf[ni] = *(const short8*)(&Bl[(wn * 64 + ni * 16 + li) * 32 + lg * 8]);
#pragma unroll
        for (int mi = 0; mi < 4; ++mi)
#pragma unroll
            for (int ni = 0; ni < 4; ++ni)
                acc[mi][ni] = mfma16(af[mi], bf[ni], acc[mi][ni]);
        __syncthreads();
    }

    if constexpr (C_MODE == 2) {
#pragma unroll
        for (int ni = 0; ni < 4; ++ni) {
            const int cc = wn * 64 + ni * 16 + li;
            const float bv = bias[bcol + cc] * bscale;
#pragma unroll
            for (int mi = 0; mi < 4; ++mi)
#pragma unroll
                for (int r = 0; r < 4; ++r) {
                    const int rr = wm * 64 + mi * 16 + lg * 4 + r;
                    Cl[cc * 132 + rr] = f2bf(acc[mi][ni][r] + bv);
                }
        }
        __syncthreads();
        const int row = tid >> 1;
        const int hcol = (tid & 1) * 64;
        u16* dst = (u16*)Cp + (size_t)(bcol + row) * M + brow + hcol;
#pragma unroll
        for (int c = 0; c < 8; ++c)
            *(short8*)(dst + c * 8) = *(const short8*)(&Cl[row * 132 + hcol + c * 8]);
    } else {
#pragma unroll
        for (int ni = 0; ni < 4; ++ni) {
            const int col = bcol + wn * 64 + ni * 16 + li;
            const float bv = bias[col] * bscale;
#pragma unroll
            for (int mi = 0; mi < 4; ++mi) {
#pragma unroll
                for (int r = 0; r < 4; ++r) {
                    const int row = brow + wm * 64 + mi * 16 + lg * 4 + r;
                    const float v = acc[mi][ni][r] + bv;
                    if (C_MODE == 1) ((u16*)Cp)[(size_t)row * N + col] = f2bf(v);
                    else             ((float*)Cp)[(size_t)row * N + col] = v;
                }
            }
        }
    }
}

// Flash attention, causal, swapped-QK^T (S^T = K·Q^T so q is lane-local).
// Double-buffered K/V staging (T3 minimum 2-phase): issue tile t+1's
// global_load_lds before computing tile t; one vmcnt-drain + barrier per tile.
__global__ __launch_bounds__(256) void flash_attn(
    const u16* __restrict__ Q, const u16* __restrict__ Kp,
    const u16* __restrict__ Vt, u16* __restrict__ O)
{
    constexpr int SP = 72;
    __shared__ u16 Kl[2][64 * 128];  // K tile [kv][128 d], XOR-swizzled
    __shared__ u16 Vl[2][128 * 64];  // V^T tile [d][64 kv], XOR-swizzled
    __shared__ u16 Pl[4 * 16 * SP];  // per-wave P [16 q][64 kv]

    const int tid = threadIdx.x;
    const int wid = tid >> 6, lane = tid & 63;
    const int lg = lane >> 4, li = lane & 15;
    const int qt = (int)gridDim.x - 1 - (int)blockIdx.x;  // heavy tiles first
    const int h = blockIdx.y, b = blockIdx.z;
    const int qloc = wid * 16 + li;                       // q within 64-tile

    // precomputed staging addresses (per-thread constants)
    const int C0 = tid;            // K: rows 0..15,  V: rows 0..31
    const int rK0 = C0 >> 4, wK0 = C0 & 15;
    const int bK0 = ((wK0 * 16) ^ ((rK0 & 7) << 4)) >> 1;
    const int rV0 = C0 >> 3, wV0 = C0 & 7;
    const int bV0 = ((wV0 * 16) ^ ((rV0 & 7) << 4)) >> 1;
    const u16* kbase = Kp + (size_t)(b * SS + rK0) * DD + h * HDIM + bK0;
    const u16* vbase = Vt + (size_t)(h * HDIM + rV0) * MM + b * SS + bV0;

#define STAGE(KT, BUF)                                                         \
    do {                                                                       \
        _Pragma("unroll")                                                      \
        for (int i_ = 0; i_ < 4; ++i_) {                                       \
            gload_lds16(kbase + (size_t)((KT) * 64 + i_ * 16) * DD,            \
                        &Kl[BUF][(i_ * 256 + tid) * 8]);                       \
            gload_lds16(vbase + (size_t)(i_ * 32) * MM + (KT) * 64,            \
                        &Vl[BUF][(i_ * 256 + tid) * 8]);                       \
        }                                                                      \
    } while (0)

    STAGE(0, 0);

    short8 qf[4];
    {
        const u16* qp = Q + (size_t)(b * SS + qt * 64 + qloc) * DD + h * HDIM + lg * 8;
#pragma unroll
        for (int s = 0; s < 4; ++s) qf[s] = *(const short8*)(qp + s * 32);
    }

    const f32x4 zero = {0.f, 0.f, 0.f, 0.f};
    float m_r = -__builtin_inff(), l_r = 0.f;
    f32x4 accO[8];                    // O^T: reg r -> d = mb*16+lg*4+r, col -> q = li
#pragma unroll
    for (int d = 0; d < 8; ++d) accO[d] = zero;

    __syncthreads();                  // compiler drains vmcnt before barrier

    for (int kt = 0; kt <= qt; ++kt) {
        const int cur = kt & 1;
        if (kt < qt) STAGE(kt + 1, cur ^ 1);    // prefetch next tile (block-uniform)

        // ---- scores TRANSPOSED: S^T[64 kv][16 q], A=K, B=Q ----
        f32x4 accS[4] = {zero, zero, zero, zero};
        __builtin_amdgcn_s_setprio(1);
#pragma unroll
        for (int s = 0; s < 4; ++s) {
#pragma unroll
            for (int nb = 0; nb < 4; ++nb) {
                const int R = nb * 16 + li;
                const int e = ((s * 64 + lg * 16) ^ ((R & 7) << 4)) >> 1;
                short8 kf = *(const short8*)(&Kl[cur][R * 128 + e]);
                accS[nb] = mfma16(kf, qf[s], accS[nb]);   // swapped: A=K, B=Q
            }
        }
        __builtin_amdgcn_s_setprio(0);

        // ---- online softmax, per-lane (q = li), exp2 domain ----
        float p[4][4];
        float rmax = -__builtin_inff();
        const bool diag = (kt == qt);
#pragma unroll
        for (int nb = 0; nb < 4; ++nb)
#pragma unroll
            for (int r = 0; r < 4; ++r) {
                float t = accS[nb][r];                    // kv = nb*16+lg*4+r
                if (diag && (nb * 16 + lg * 4 + r > qloc)) t = -__builtin_inff();
                p[nb][r] = t;
                rmax = fmaxf(rmax, t);
            }
        rmax = fmaxf(rmax, __shfl_xor(rmax, 16, 64));
        rmax = fmaxf(rmax, __shfl_xor(rmax, 32, 64));

        // defer-max (T13): skip rescale while max growth is small
        if (!__all(rmax - m_r <= 11.5f)) {
            const float mn = fmaxf(m_r, rmax);
            const float sf = exp2f(m_r - mn);
            m_r = mn;
            l_r *= sf;
#pragma unroll
            for (int mb = 0; mb < 8; ++mb)
#pragma unroll
                for (int r = 0; r < 4; ++r) accO[mb][r] *= sf;
        }

        float ls = 0.f;
#pragma unroll
        for (int nb = 0; nb < 4; ++nb)
#pragma unroll
            for (int r = 0; r < 4; ++r) {
                const float e = exp2f(p[nb][r] - m_r);
                p[nb][r] = e;
                ls += e;
            }
        ls += __shfl_xor(ls, 16, 64);
        ls += __shfl_xor(ls, 32, 64);
        l_r += ls;

        // ---- P^T -> row-major P[q][kv] in LDS (intra-wave produce/consume) ----
#pragma unroll
        for (int nb = 0; nb < 4; ++nb)
#pragma unroll
            for (int r = 0; r < 4; ++r)
                Pl[(wid * 16 + li) * SP + nb * 16 + lg * 4 + r] = f2bf(p[nb][r]);

        // ---- PV transposed: O^T[128 d][16 q] += V^T[128][64] @ P^T[64][16] ----
        __builtin_amdgcn_s_setprio(1);
#pragma unroll
        for (int s2 = 0; s2 < 2; ++s2) {
            short8 pf = *(const short8*)(&Pl[(wid * 16 + li) * SP + s2 * 32 + lg * 8]);
#pragma unroll
            for (int mb = 0; mb < 8; ++mb) {
                const int R2 = mb * 16 + li;
                const int e2 = ((s2 * 64 + lg * 16) ^ ((R2 & 7) << 4)) >> 1;
                short8 vf = *(const short8*)(&Vl[cur][R2 * 64 + e2]);
                accO[mb] = mfma16(vf, pf, accO[mb]);
            }
        }
        __builtin_amdgcn_s_setprio(0);
        __syncthreads();              // drains the prefetch (vmcnt) + LDS, flips buffers
    }
#undef STAGE

    // ---- epilogue: un-transpose via per-wave LDS bounce (reuse Kl[0]) ----
    {
        const float linv = 1.f / l_r;                 // per-lane: q = li
        u16* Wl = &Kl[0][0] + wid * 2048;             // 16 q x 128 d per wave
#pragma unroll
        for (int mb = 0; mb < 8; ++mb)
#pragma unroll
            for (int r = 0; r < 4; ++r) {
                const int d = mb * 16 + lg * 4 + r;
                Wl[li * 128 + (d ^ ((li & 7) << 4))] = f2bf(accO[mb][r] * linv);
            }
        const int q = lane >> 2;
        const int d0 = (lane & 3) * 32;
        u16* op = O + (size_t)(b * SS + qt * 64 + wid * 16 + q) * DD + h * HDIM + d0;
#pragma unroll
        for (int c = 0; c < 4; ++c) {
            short8 vv = *(const short8*)(&Wl[q * 128 + ((d0 + c * 8) ^ ((q & 7) << 4))]);
            *(short8*)(op + c * 8) = vv;
        }
    }
}

extern "C" void kernel_launch(void* const* d_in, const int* in_sizes, int n_in,
                              void* d_out, int out_size, void* d_ws, size_t ws_size,
                              hipStream_t stream)
{
    const float* queries = (const float*)d_in[0];
    const float* keys    = (const float*)d_in[1];
    const float* values  = (const float*)d_in[2];
    // d_in[3] = attention_mask: causal by construction
    const float* wq = (const float*)d_in[4];
    const float* bq = (const float*)d_in[5];
    const float* wk = (const float*)d_in[6];
    const float* bk = (const float*)d_in[7];
    const float* wv = (const float*)d_in[8];
    const float* bv = (const float*)d_in[9];
    const float* wo = (const float*)d_in[10];
    const float* bo = (const float*)d_in[11];

    const int M   = MM;
    const int NMD = M * DD;
    const int NWW = DD * DD;

    u16* qb  = (u16*)d_ws;
    u16* kb  = qb  + (size_t)NMD;
    u16* vb  = kb  + (size_t)NMD;
    u16* wqb = vb  + (size_t)NMD;               // pre-scaled by KSCALE
    u16* wkb = wqb + (size_t)NWW;
    u16* wvb = wkb + (size_t)NWW;
    u16* wob = wvb + (size_t)NWW;
    u16* qw  = wob + (size_t)NWW;               // q proj (bf16 [M][D], KSCALE folded)
    u16* kw  = qw  + (size_t)NMD;               // k proj (bf16 [M][D])
    u16* vtw = kw  + (size_t)NMD;               // v proj TRANSPOSED ([D][M])
    u16* aw  = vtw + (size_t)NMD;               // attention output (bf16 [M][D])
    (void)in_sizes; (void)n_in; (void)out_size; (void)ws_size;

    dim3 blk(256);
    dim3 gridC(2048);
    dim3 gridG(M / 128, DD / 128);              // (32, 16)
    dim3 gridA(SS / 64, HH, BB);                // (32, 16, 2)

    conv_all<<<gridC, blk, 0, stream>>>(queries, keys, values, wq, wk, wv, wo, qb);

    gemm_bf16<1><<<gridG, blk, 0, stream>>>(qb, wqb, bq, qw,  M, DD, DD, KSCALE);
    gemm_bf16<1><<<gridG, blk, 0, stream>>>(kb, wkb, bk, kw,  M, DD, DD, 1.f);
    gemm_bf16<2><<<gridG, blk, 0, stream>>>(vb, wvb, bv, vtw, M, DD, DD, 1.f);
    flash_attn<<<gridA, blk, 0, stream>>>(qw, kw, vtw, aw);
    gemm_bf16<0><<<gridG, blk, 0, stream>>>(aw, wob, bo, (float*)d_out, M, DD, DD, 1.f);
}